// Round 2
// baseline (463.742 us; speedup 1.0000x reference)
//
#include <hip/hip_runtime.h>
#include <hip/hip_bf16.h>

// ---------- problem constants ----------
#define N_NODES 50000
#define N_EDGES 800000
#define C_DIM   256      // IN_C == HID_C
#define OUT_C   128
#define N_GRAPHS 256

typedef unsigned short ushort8 __attribute__((ext_vector_type(8)));
typedef __bf16         bf16x8  __attribute__((ext_vector_type(8)));
typedef float          f32x4   __attribute__((ext_vector_type(4)));

__device__ __forceinline__ float us2f(unsigned short u) {
    unsigned int x = ((unsigned int)u) << 16;
    return __builtin_bit_cast(float, x);
}
__device__ __forceinline__ unsigned short f2bf(float f) {
    unsigned int u = __builtin_bit_cast(unsigned int, f);
    u += 0x7fffu + ((u >> 16) & 1u);   // RNE
    return (unsigned short)(u >> 16);
}

__device__ __forceinline__ int lower_bound_i(const int* __restrict__ a, int n, int v) {
    int lo = 0, hi = n;
    while (lo < hi) {
        int mid = (lo + hi) >> 1;
        if (a[mid] < v) lo = mid + 1; else hi = mid;
    }
    return lo;
}

// ---------- K1: CSR pointers from sorted dst / sorted batch ----------
__global__ void build_ptrs(const int* __restrict__ dst, const int* __restrict__ batch,
                           int* __restrict__ row_ptr, int* __restrict__ graph_ptr) {
    int i = blockIdx.x * blockDim.x + threadIdx.x;
    if (i <= N_NODES)  row_ptr[i]   = lower_bound_i(dst,   N_EDGES, i);
    if (i <= N_GRAPHS) graph_ptr[i] = lower_bound_i(batch, N_NODES, i);
}

// ---------- K2: inverse degree ----------
__global__ void inv_deg_k(const int* __restrict__ row_ptr, float* __restrict__ inv_deg) {
    int i = blockIdx.x * blockDim.x + threadIdx.x;
    if (i < N_NODES) {
        int cnt = row_ptr[i + 1] - row_ptr[i];
        inv_deg[i] = (cnt > 0) ? (1.0f / (float)cnt) : 0.0f;
    }
}

// ---------- K3: f32 -> bf16 elementwise convert (x -> xb), 4 elems/thread ----------
__global__ void convert_bf16(const float* __restrict__ S, unsigned short* __restrict__ D) {
    int i = blockIdx.x * blockDim.x + threadIdx.x;   // element group of 4
    float4 v = *(const float4*)(S + ((size_t)i << 2));
    ushort4 o;
    o.x = f2bf(v.x); o.y = f2bf(v.y); o.z = f2bf(v.z); o.w = f2bf(v.w);
    *(ushort4*)(D + ((size_t)i << 2)) = o;
}

// ---------- K4: transpose + convert 256x256 f32 weight (K-major -> N-major bf16) ----------
__global__ void transpose256(const float* __restrict__ S, unsigned short* __restrict__ D) {
    int i = blockIdx.x * 256 + threadIdx.x;   // i = k*256 + n
    int k = i >> 8, n = i & 255;
    D[n * 256 + k] = f2bf(S[i]);
}

// ---------- K5: mean aggregation over incoming edges (bf16 in, bf16 out, f32 accum) ----------
// one wave per node, lane handles 4 channels (ushort4 = 8B loads; 512B/edge-row)
__global__ void aggregate(const unsigned short* __restrict__ X,
                          const int* __restrict__ src,
                          const int* __restrict__ row_ptr,
                          const float* __restrict__ inv_deg,
                          unsigned short* __restrict__ out) {
    int gw   = (blockIdx.x * blockDim.x + threadIdx.x) >> 6;
    int lane = threadIdx.x & 63;
    if (gw >= N_NODES) return;
    int e0 = row_ptr[gw], e1 = row_ptr[gw + 1];
    float a0 = 0.f, a1 = 0.f, a2 = 0.f, a3 = 0.f;
    for (int e = e0; e < e1; ++e) {
        int s = src[e];
        ushort4 v = *(const ushort4*)(X + ((size_t)s << 8) + (lane << 2));
        a0 += us2f(v.x); a1 += us2f(v.y); a2 += us2f(v.z); a3 += us2f(v.w);
    }
    float sc = inv_deg[gw];
    ushort4 o;
    o.x = f2bf(a0 * sc); o.y = f2bf(a1 * sc); o.z = f2bf(a2 * sc); o.w = f2bf(a3 * sc);
    *(ushort4*)(out + ((size_t)gw << 8) + (lane << 2)) = o;
}

// ---------- K6: fused SAGE GEMM: C = A1@B1 + A2@B2 + bias, optional ReLU ----------
// A1,A2: [M x 256] bf16 row-major.  B1t,B2t: [256(N) x 256(K)] bf16 (transposed).
// bias f32. C bf16. Tile 128x128, 4 waves (2x2), each wave 4x4 MFMA 16x16x32.
__global__ __launch_bounds__(256, 2)
void gemm_fused(const unsigned short* __restrict__ A1,
                const unsigned short* __restrict__ A2,
                const unsigned short* __restrict__ B1t,
                const unsigned short* __restrict__ B2t,
                const float* __restrict__ bias,
                unsigned short* __restrict__ C,
                int M, int do_relu) {
    __shared__ __align__(16) unsigned short As[128][40];  // +8 pad, rows stay 16B aligned
    __shared__ __align__(16) unsigned short Bs[128][40];

    const int t    = threadIdx.x;
    const int m0   = blockIdx.x * 128;
    const int n0   = blockIdx.y * 128;
    const int lane = t & 63, wid = t >> 6;
    const int wm   = (wid >> 1) * 64;       // wave row offset in tile
    const int wn   = (wid & 1) * 64;        // wave col offset in tile
    const int lrow = lane & 15;
    const int koff = (lane >> 4) * 8;

    const f32x4 zero4 = {0.f, 0.f, 0.f, 0.f};
    f32x4 acc[4][4];
#pragma unroll
    for (int i = 0; i < 4; ++i)
#pragma unroll
        for (int j = 0; j < 4; ++j) acc[i][j] = zero4;

    const ushort8 zero8 = {0, 0, 0, 0, 0, 0, 0, 0};

    for (int it = 0; it < 16; ++it) {       // K = 512 virtual (2 x 256)
        int kt = it * 32;
        const unsigned short* __restrict__ Ab = (kt < 256) ? A1 : A2;
        const unsigned short* __restrict__ Bb = (kt < 256) ? B1t : B2t;
        int ko = kt & 255;

        // stage A-tile (128x32) and B-tile (128n x 32k), 2 x 16B per thread each
#pragma unroll
        for (int i = 0; i < 2; ++i) {
            int idx = (t + i * 256) * 8;
            int r = idx >> 5, c = idx & 31;
            int gr = m0 + r;
            ushort8 va = zero8;
            if (gr < M) va = *(const ushort8*)(Ab + (size_t)gr * 256 + ko + c);
            *(ushort8*)&As[r][c] = va;
            int gn = n0 + r;                 // always < 256
            ushort8 vb = *(const ushort8*)(Bb + (size_t)gn * 256 + ko + c);
            *(ushort8*)&Bs[r][c] = vb;
        }
        __syncthreads();

        bf16x8 af[4], bfr[4];
#pragma unroll
        for (int mi = 0; mi < 4; ++mi) {
            uint4 u = *(const uint4*)&As[wm + mi * 16 + lrow][koff];
            af[mi] = __builtin_bit_cast(bf16x8, u);
        }
#pragma unroll
        for (int ni = 0; ni < 4; ++ni) {
            uint4 u = *(const uint4*)&Bs[wn + ni * 16 + lrow][koff];
            bfr[ni] = __builtin_bit_cast(bf16x8, u);
        }
#pragma unroll
        for (int mi = 0; mi < 4; ++mi)
#pragma unroll
            for (int ni = 0; ni < 4; ++ni)
                acc[mi][ni] = __builtin_amdgcn_mfma_f32_16x16x32_bf16(
                    af[mi], bfr[ni], acc[mi][ni], 0, 0, 0);
        __syncthreads();
    }

    // epilogue: D mapping col = lane&15, row = (lane>>4)*4 + reg
    const int rbase = (lane >> 4) * 4;
#pragma unroll
    for (int ni = 0; ni < 4; ++ni) {
        int n  = n0 + wn + ni * 16 + lrow;
        float bv = bias[n];
#pragma unroll
        for (int mi = 0; mi < 4; ++mi) {
            int mb = m0 + wm + mi * 16 + rbase;
#pragma unroll
            for (int r = 0; r < 4; ++r) {
                int m = mb + r;
                if (m < M) {
                    float v = acc[mi][ni][r] + bv;
                    if (do_relu) v = fmaxf(v, 0.f);
                    C[(size_t)m * 256 + n] = f2bf(v);
                }
            }
        }
    }
}

// ---------- K7: per-graph p-weighted mean pool + root gather -> feat[G][512] f32 ----------
__global__ void pool_feat(const unsigned short* __restrict__ h2,
                          const float* __restrict__ p,
                          const int* __restrict__ graph_ptr,
                          const int* __restrict__ root_ptr,
                          float* __restrict__ feat) {
    int g = blockIdx.x;
    int c = threadIdx.x;        // 256 threads = channels
    int s = graph_ptr[g], e = graph_ptr[g + 1];
    float acc = 0.f;
    for (int n = s; n < e; ++n) {
        float pv = p[n];
        acc += us2f(h2[(size_t)n * 256 + c]) * pv;
    }
    float cnt = (float)(e - s);
    float gmean = acc / fmaxf(cnt, 1.0f);
    int root = root_ptr[g];
    feat[(size_t)g * 512 + c]       = us2f(h2[(size_t)root * 256 + c]);
    feat[(size_t)g * 512 + 256 + c] = gmean;
}

// ---------- K8: final linear  out = feat @ Wlin + blin  (all f32) ----------
__global__ void final_gemm(const float* __restrict__ feat,
                           const float* __restrict__ Wlin,
                           const float* __restrict__ blin,
                           float* __restrict__ out) {
    int g = blockIdx.x;
    int o = threadIdx.x;        // 128 threads
    __shared__ float fl[512];
    for (int k = o; k < 512; k += 128) fl[k] = feat[(size_t)g * 512 + k];
    __syncthreads();
    float acc = blin[o];
    for (int k = 0; k < 512; ++k)
        acc += fl[k] * Wlin[k * 128 + o];
    out[(size_t)g * 128 + o] = acc;
}

extern "C" void kernel_launch(void* const* d_in, const int* in_sizes, int n_in,
                              void* d_out, int out_size, void* d_ws, size_t ws_size,
                              hipStream_t stream) {
    // inputs: all float arrays are f32 (per the reference), ints are int32
    const float* x        = (const float*)d_in[0];
    const int*   src      = (const int*)d_in[1];
    const int*   dst      = (const int*)d_in[2];
    const float* p        = (const float*)d_in[3];
    const int*   batch    = (const int*)d_in[4];
    const int*   root_ptr = (const int*)d_in[5];
    // d_in[6] = num_graphs (256, hard-coded)
    const float* Wl1  = (const float*)d_in[7];
    const float* Wr1  = (const float*)d_in[8];
    const float* b1   = (const float*)d_in[9];
    const float* Wl2  = (const float*)d_in[10];
    const float* Wr2  = (const float*)d_in[11];
    const float* b2   = (const float*)d_in[12];
    const float* Wlin = (const float*)d_in[13];
    const float* blin = (const float*)d_in[14];
    float* out = (float*)d_out;

    // workspace layout (256B aligned slabs); total ~78 MB
    size_t off = 0;
    char* base = (char*)d_ws;
    auto alloc = [&](size_t bytes) -> void* {
        void* q = base + off;
        off += (bytes + 255) & ~(size_t)255;
        return q;
    };
    int*            row_ptr   = (int*)  alloc((N_NODES + 1) * sizeof(int));
    int*            graph_ptr = (int*)  alloc((N_GRAPHS + 1) * sizeof(int));
    float*          inv_deg   = (float*)alloc(N_NODES * sizeof(float));
    unsigned short* Wl1t = (unsigned short*)alloc(256 * 256 * 2);
    unsigned short* Wr1t = (unsigned short*)alloc(256 * 256 * 2);
    unsigned short* Wl2t = (unsigned short*)alloc(256 * 256 * 2);
    unsigned short* Wr2t = (unsigned short*)alloc(256 * 256 * 2);
    unsigned short* xb   = (unsigned short*)alloc((size_t)N_NODES * 256 * 2);
    unsigned short* aggb = (unsigned short*)alloc((size_t)N_NODES * 256 * 2);
    unsigned short* h1   = (unsigned short*)alloc((size_t)N_NODES * 256 * 2);
    unsigned short* h2   = (unsigned short*)alloc((size_t)N_NODES * 256 * 2);
    float*          feat = (float*)alloc((size_t)N_GRAPHS * 512 * sizeof(float));
    (void)ws_size; (void)n_in; (void)in_sizes; (void)out_size;

    build_ptrs<<<196, 256, 0, stream>>>(dst, batch, row_ptr, graph_ptr);
    inv_deg_k<<<196, 256, 0, stream>>>(row_ptr, inv_deg);
    convert_bf16<<<N_NODES * 256 / 4 / 256, 256, 0, stream>>>(x, xb);
    transpose256<<<256, 256, 0, stream>>>(Wl1, Wl1t);
    transpose256<<<256, 256, 0, stream>>>(Wr1, Wr1t);
    transpose256<<<256, 256, 0, stream>>>(Wl2, Wl2t);
    transpose256<<<256, 256, 0, stream>>>(Wr2, Wr2t);

    dim3 ggrid((N_NODES + 127) / 128, 2);

    // conv1: h1 = relu(agg(x)@Wl1 + x@Wr1 + b1)
    aggregate<<<N_NODES / 4, 256, 0, stream>>>(xb, src, row_ptr, inv_deg, aggb);
    gemm_fused<<<ggrid, 256, 0, stream>>>(aggb, xb, Wl1t, Wr1t, b1, h1, N_NODES, 1);

    // conv2: h2 = agg(h1)@Wl2 + h1@Wr2 + b2
    aggregate<<<N_NODES / 4, 256, 0, stream>>>(h1, src, row_ptr, inv_deg, aggb);
    gemm_fused<<<ggrid, 256, 0, stream>>>(aggb, h1, Wl2t, Wr2t, b2, h2, N_NODES, 0);

    // pool + root gather + final linear
    pool_feat<<<N_GRAPHS, 256, 0, stream>>>(h2, p, graph_ptr, root_ptr, feat);
    final_gemm<<<N_GRAPHS, 128, 0, stream>>>(feat, Wlin, blin, out);
}

// Round 3
// 392.873 us; speedup vs baseline: 1.1804x; 1.1804x over previous
//
#include <hip/hip_runtime.h>
#include <hip/hip_bf16.h>

// ---------- problem constants ----------
#define N_NODES 50000
#define N_EDGES 800000
#define C_DIM   256      // IN_C == HID_C
#define OUT_C   128
#define N_GRAPHS 256

typedef unsigned short ushort8 __attribute__((ext_vector_type(8)));
typedef __bf16         bf16x8  __attribute__((ext_vector_type(8)));
typedef float          f32x4   __attribute__((ext_vector_type(4)));

__device__ __forceinline__ float us2f(unsigned short u) {
    unsigned int x = ((unsigned int)u) << 16;
    return __builtin_bit_cast(float, x);
}
__device__ __forceinline__ unsigned short f2bf(float f) {
    unsigned int u = __builtin_bit_cast(unsigned int, f);
    u += 0x7fffu + ((u >> 16) & 1u);   // RNE
    return (unsigned short)(u >> 16);
}

__device__ __forceinline__ int lower_bound_i(const int* __restrict__ a, int n, int v) {
    int lo = 0, hi = n;
    while (lo < hi) {
        int mid = (lo + hi) >> 1;
        if (a[mid] < v) lo = mid + 1; else hi = mid;
    }
    return lo;
}

// ---------- K1: CSR pointers + inv_deg in one kernel ----------
__global__ void build_ptrs(const int* __restrict__ dst, const int* __restrict__ batch,
                           int* __restrict__ row_ptr, int* __restrict__ graph_ptr,
                           float* __restrict__ inv_deg) {
    int i = blockIdx.x * blockDim.x + threadIdx.x;
    if (i <= N_NODES) {
        int lb = lower_bound_i(dst, N_EDGES, i);
        row_ptr[i] = lb;
        if (i < N_NODES) {
            int ub = lower_bound_i(dst, N_EDGES, i + 1);
            int cnt = ub - lb;
            inv_deg[i] = (cnt > 0) ? (1.0f / (float)cnt) : 0.0f;
        }
    }
    if (i <= N_GRAPHS) graph_ptr[i] = lower_bound_i(batch, N_NODES, i);
}

// ---------- K2: f32 -> bf16 elementwise convert (x -> xb), 4 elems/thread ----------
__global__ void convert_bf16(const float* __restrict__ S, unsigned short* __restrict__ D) {
    int i = blockIdx.x * blockDim.x + threadIdx.x;   // element group of 4
    float4 v = *(const float4*)(S + ((size_t)i << 2));
    ushort4 o;
    o.x = f2bf(v.x); o.y = f2bf(v.y); o.z = f2bf(v.z); o.w = f2bf(v.w);
    *(ushort4*)(D + ((size_t)i << 2)) = o;
}

// ---------- K3: transpose + convert all four 256x256 f32 weights -> N-major bf16 ----------
__global__ void transpose256x4(const float* __restrict__ S0, const float* __restrict__ S1,
                               const float* __restrict__ S2, const float* __restrict__ S3,
                               unsigned short* __restrict__ D0, unsigned short* __restrict__ D1,
                               unsigned short* __restrict__ D2, unsigned short* __restrict__ D3) {
    const float* S; unsigned short* D;
    switch (blockIdx.y) {
        case 0: S = S0; D = D0; break;
        case 1: S = S1; D = D1; break;
        case 2: S = S2; D = D2; break;
        default: S = S3; D = D3; break;
    }
    int i = blockIdx.x * 256 + threadIdx.x;   // i = k*256 + n
    int k = i >> 8, n = i & 255;
    D[n * 256 + k] = f2bf(S[i]);
}

// ---------- K4: mean aggregation (bf16 in/out, f32 accum), MLP-unrolled x8 ----------
// one wave per node, lane handles 4 channels (ushort4 = 8B loads; 512B/edge-row)
__global__ void aggregate(const unsigned short* __restrict__ X,
                          const int* __restrict__ src,
                          const int* __restrict__ row_ptr,
                          const float* __restrict__ inv_deg,
                          unsigned short* __restrict__ out) {
    int gw   = (blockIdx.x * blockDim.x + threadIdx.x) >> 6;
    int lane = threadIdx.x & 63;
    if (gw >= N_NODES) return;
    int e0 = row_ptr[gw], e1 = row_ptr[gw + 1];
    float a0 = 0.f, a1 = 0.f, a2 = 0.f, a3 = 0.f;
    const int lo = lane << 2;
    int e = e0;
    // 8 independent gathers in flight per iteration (latency hiding)
    for (; e + 8 <= e1; e += 8) {
        int s0 = src[e + 0], s1 = src[e + 1], s2 = src[e + 2], s3 = src[e + 3];
        int s4 = src[e + 4], s5 = src[e + 5], s6 = src[e + 6], s7 = src[e + 7];
        ushort4 v0 = *(const ushort4*)(X + ((size_t)s0 << 8) + lo);
        ushort4 v1 = *(const ushort4*)(X + ((size_t)s1 << 8) + lo);
        ushort4 v2 = *(const ushort4*)(X + ((size_t)s2 << 8) + lo);
        ushort4 v3 = *(const ushort4*)(X + ((size_t)s3 << 8) + lo);
        ushort4 v4 = *(const ushort4*)(X + ((size_t)s4 << 8) + lo);
        ushort4 v5 = *(const ushort4*)(X + ((size_t)s5 << 8) + lo);
        ushort4 v6 = *(const ushort4*)(X + ((size_t)s6 << 8) + lo);
        ushort4 v7 = *(const ushort4*)(X + ((size_t)s7 << 8) + lo);
        a0 += us2f(v0.x) + us2f(v1.x) + us2f(v2.x) + us2f(v3.x)
            + us2f(v4.x) + us2f(v5.x) + us2f(v6.x) + us2f(v7.x);
        a1 += us2f(v0.y) + us2f(v1.y) + us2f(v2.y) + us2f(v3.y)
            + us2f(v4.y) + us2f(v5.y) + us2f(v6.y) + us2f(v7.y);
        a2 += us2f(v0.z) + us2f(v1.z) + us2f(v2.z) + us2f(v3.z)
            + us2f(v4.z) + us2f(v5.z) + us2f(v6.z) + us2f(v7.z);
        a3 += us2f(v0.w) + us2f(v1.w) + us2f(v2.w) + us2f(v3.w)
            + us2f(v4.w) + us2f(v5.w) + us2f(v6.w) + us2f(v7.w);
    }
    for (; e < e1; ++e) {
        int s = src[e];
        ushort4 v = *(const ushort4*)(X + ((size_t)s << 8) + lo);
        a0 += us2f(v.x); a1 += us2f(v.y); a2 += us2f(v.z); a3 += us2f(v.w);
    }
    float sc = inv_deg[gw];
    ushort4 o;
    o.x = f2bf(a0 * sc); o.y = f2bf(a1 * sc); o.z = f2bf(a2 * sc); o.w = f2bf(a3 * sc);
    *(ushort4*)(out + ((size_t)gw << 8) + lo) = o;
}

// ---------- K5: fused SAGE GEMM: C = A1@B1 + A2@B2 + bias, optional ReLU ----------
// A1,A2: [M x 256] bf16 row-major.  B1t,B2t: [256(N) x 256(K)] bf16 (transposed).
// bias f32. C bf16. Tile 128x128, 4 waves (2x2), each wave 4x4 MFMA 16x16x32.
__global__ __launch_bounds__(256, 2)
void gemm_fused(const unsigned short* __restrict__ A1,
                const unsigned short* __restrict__ A2,
                const unsigned short* __restrict__ B1t,
                const unsigned short* __restrict__ B2t,
                const float* __restrict__ bias,
                unsigned short* __restrict__ C,
                int M, int do_relu) {
    __shared__ __align__(16) unsigned short As[128][40];  // +8 pad, rows stay 16B aligned
    __shared__ __align__(16) unsigned short Bs[128][40];

    const int t    = threadIdx.x;
    const int m0   = blockIdx.x * 128;
    const int n0   = blockIdx.y * 128;
    const int lane = t & 63, wid = t >> 6;
    const int wm   = (wid >> 1) * 64;       // wave row offset in tile
    const int wn   = (wid & 1) * 64;        // wave col offset in tile
    const int lrow = lane & 15;
    const int koff = (lane >> 4) * 8;

    const f32x4 zero4 = {0.f, 0.f, 0.f, 0.f};
    f32x4 acc[4][4];
#pragma unroll
    for (int i = 0; i < 4; ++i)
#pragma unroll
        for (int j = 0; j < 4; ++j) acc[i][j] = zero4;

    const ushort8 zero8 = {0, 0, 0, 0, 0, 0, 0, 0};

    for (int it = 0; it < 16; ++it) {       // K = 512 virtual (2 x 256)
        int kt = it * 32;
        const unsigned short* __restrict__ Ab = (kt < 256) ? A1 : A2;
        const unsigned short* __restrict__ Bb = (kt < 256) ? B1t : B2t;
        int ko = kt & 255;

        // stage A-tile (128x32) and B-tile (128n x 32k), 2 x 16B per thread each
#pragma unroll
        for (int i = 0; i < 2; ++i) {
            int idx = (t + i * 256) * 8;
            int r = idx >> 5, c = idx & 31;
            int gr = m0 + r;
            ushort8 va = zero8;
            if (gr < M) va = *(const ushort8*)(Ab + (size_t)gr * 256 + ko + c);
            *(ushort8*)&As[r][c] = va;
            int gn = n0 + r;                 // always < 256
            ushort8 vb = *(const ushort8*)(Bb + (size_t)gn * 256 + ko + c);
            *(ushort8*)&Bs[r][c] = vb;
        }
        __syncthreads();

        bf16x8 af[4], bfr[4];
#pragma unroll
        for (int mi = 0; mi < 4; ++mi) {
            uint4 u = *(const uint4*)&As[wm + mi * 16 + lrow][koff];
            af[mi] = __builtin_bit_cast(bf16x8, u);
        }
#pragma unroll
        for (int ni = 0; ni < 4; ++ni) {
            uint4 u = *(const uint4*)&Bs[wn + ni * 16 + lrow][koff];
            bfr[ni] = __builtin_bit_cast(bf16x8, u);
        }
#pragma unroll
        for (int mi = 0; mi < 4; ++mi)
#pragma unroll
            for (int ni = 0; ni < 4; ++ni)
                acc[mi][ni] = __builtin_amdgcn_mfma_f32_16x16x32_bf16(
                    af[mi], bfr[ni], acc[mi][ni], 0, 0, 0);
        __syncthreads();
    }

    // epilogue: D mapping col = lane&15, row = (lane>>4)*4 + reg
    const int rbase = (lane >> 4) * 4;
#pragma unroll
    for (int ni = 0; ni < 4; ++ni) {
        int n  = n0 + wn + ni * 16 + lrow;
        float bv = bias[n];
#pragma unroll
        for (int mi = 0; mi < 4; ++mi) {
            int mb = m0 + wm + mi * 16 + rbase;
#pragma unroll
            for (int r = 0; r < 4; ++r) {
                int m = mb + r;
                if (m < M) {
                    float v = acc[mi][ni][r] + bv;
                    if (do_relu) v = fmaxf(v, 0.f);
                    C[(size_t)m * 256 + n] = f2bf(v);
                }
            }
        }
    }
}

// ---------- K6: per-graph p-weighted mean pool + root gather -> feat[G][512] f32 ----------
__global__ void pool_feat(const unsigned short* __restrict__ h2,
                          const float* __restrict__ p,
                          const int* __restrict__ graph_ptr,
                          const int* __restrict__ root_ptr,
                          float* __restrict__ feat) {
    int g = blockIdx.x;
    int c = threadIdx.x;        // 256 threads = channels
    int s = graph_ptr[g], e = graph_ptr[g + 1];
    float acc = 0.f;
    for (int n = s; n < e; ++n) {
        float pv = p[n];
        acc += us2f(h2[(size_t)n * 256 + c]) * pv;
    }
    float cnt = (float)(e - s);
    float gmean = acc / fmaxf(cnt, 1.0f);
    int root = root_ptr[g];
    feat[(size_t)g * 512 + c]       = us2f(h2[(size_t)root * 256 + c]);
    feat[(size_t)g * 512 + 256 + c] = gmean;
}

// ---------- K7: final linear  out = feat @ Wlin + blin  (all f32) ----------
__global__ void final_gemm(const float* __restrict__ feat,
                           const float* __restrict__ Wlin,
                           const float* __restrict__ blin,
                           float* __restrict__ out) {
    int g = blockIdx.x;
    int o = threadIdx.x;        // 128 threads
    __shared__ float fl[512];
    for (int k = o; k < 512; k += 128) fl[k] = feat[(size_t)g * 512 + k];
    __syncthreads();
    float acc = blin[o];
    for (int k = 0; k < 512; ++k)
        acc += fl[k] * Wlin[k * 128 + o];
    out[(size_t)g * 128 + o] = acc;
}

extern "C" void kernel_launch(void* const* d_in, const int* in_sizes, int n_in,
                              void* d_out, int out_size, void* d_ws, size_t ws_size,
                              hipStream_t stream) {
    // inputs: all float arrays are f32 (per the reference), ints are int32
    const float* x        = (const float*)d_in[0];
    const int*   src      = (const int*)d_in[1];
    const int*   dst      = (const int*)d_in[2];
    const float* p        = (const float*)d_in[3];
    const int*   batch    = (const int*)d_in[4];
    const int*   root_ptr = (const int*)d_in[5];
    // d_in[6] = num_graphs (256, hard-coded)
    const float* Wl1  = (const float*)d_in[7];
    const float* Wr1  = (const float*)d_in[8];
    const float* b1   = (const float*)d_in[9];
    const float* Wl2  = (const float*)d_in[10];
    const float* Wr2  = (const float*)d_in[11];
    const float* b2   = (const float*)d_in[12];
    const float* Wlin = (const float*)d_in[13];
    const float* blin = (const float*)d_in[14];
    float* out = (float*)d_out;

    // workspace layout (256B aligned slabs); total ~78 MB
    size_t off = 0;
    char* base = (char*)d_ws;
    auto alloc = [&](size_t bytes) -> void* {
        void* q = base + off;
        off += (bytes + 255) & ~(size_t)255;
        return q;
    };
    int*            row_ptr   = (int*)  alloc((N_NODES + 1) * sizeof(int));
    int*            graph_ptr = (int*)  alloc((N_GRAPHS + 1) * sizeof(int));
    float*          inv_deg   = (float*)alloc(N_NODES * sizeof(float));
    unsigned short* Wl1t = (unsigned short*)alloc(256 * 256 * 2);
    unsigned short* Wr1t = (unsigned short*)alloc(256 * 256 * 2);
    unsigned short* Wl2t = (unsigned short*)alloc(256 * 256 * 2);
    unsigned short* Wr2t = (unsigned short*)alloc(256 * 256 * 2);
    unsigned short* xb   = (unsigned short*)alloc((size_t)N_NODES * 256 * 2);
    unsigned short* aggb = (unsigned short*)alloc((size_t)N_NODES * 256 * 2);
    unsigned short* h1   = (unsigned short*)alloc((size_t)N_NODES * 256 * 2);
    unsigned short* h2   = (unsigned short*)alloc((size_t)N_NODES * 256 * 2);
    float*          feat = (float*)alloc((size_t)N_GRAPHS * 512 * sizeof(float));
    (void)ws_size; (void)n_in; (void)in_sizes; (void)out_size;

    build_ptrs<<<196, 256, 0, stream>>>(dst, batch, row_ptr, graph_ptr, inv_deg);
    convert_bf16<<<N_NODES * 256 / 4 / 256, 256, 0, stream>>>(x, xb);
    transpose256x4<<<dim3(256, 4), 256, 0, stream>>>(Wl1, Wr1, Wl2, Wr2,
                                                     Wl1t, Wr1t, Wl2t, Wr2t);

    dim3 ggrid((N_NODES + 127) / 128, 2);

    // conv1: h1 = relu(agg(x)@Wl1 + x@Wr1 + b1)
    aggregate<<<N_NODES / 4, 256, 0, stream>>>(xb, src, row_ptr, inv_deg, aggb);
    gemm_fused<<<ggrid, 256, 0, stream>>>(aggb, xb, Wl1t, Wr1t, b1, h1, N_NODES, 1);

    // conv2: h2 = agg(h1)@Wl2 + h1@Wr2 + b2
    aggregate<<<N_NODES / 4, 256, 0, stream>>>(h1, src, row_ptr, inv_deg, aggb);
    gemm_fused<<<ggrid, 256, 0, stream>>>(aggb, h1, Wl2t, Wr2t, b2, h2, N_NODES, 0);

    // pool + root gather + final linear
    pool_feat<<<N_GRAPHS, 256, 0, stream>>>(h2, p, graph_ptr, root_ptr, feat);
    final_gemm<<<N_GRAPHS, 128, 0, stream>>>(feat, Wlin, blin, out);
}

// Round 4
// 380.628 us; speedup vs baseline: 1.2184x; 1.0322x over previous
//
#include <hip/hip_runtime.h>
#include <hip/hip_bf16.h>

// ---------- problem constants ----------
#define N_NODES 50000
#define N_EDGES 800000
#define C_DIM   256      // IN_C == HID_C
#define OUT_C   128
#define N_GRAPHS 256

typedef unsigned short ushort8 __attribute__((ext_vector_type(8)));
typedef __bf16         bf16x8  __attribute__((ext_vector_type(8)));
typedef float          f32x4   __attribute__((ext_vector_type(4)));

typedef __attribute__((address_space(1))) const unsigned int gu32;
typedef __attribute__((address_space(3))) unsigned int lu32;

__device__ __forceinline__ float us2f(unsigned short u) {
    unsigned int x = ((unsigned int)u) << 16;
    return __builtin_bit_cast(float, x);
}
__device__ __forceinline__ unsigned short f2bf(float f) {
    unsigned int u = __builtin_bit_cast(unsigned int, f);
    u += 0x7fffu + ((u >> 16) & 1u);   // RNE
    return (unsigned short)(u >> 16);
}

__device__ __forceinline__ int lower_bound_i(const int* __restrict__ a, int n, int v) {
    int lo = 0, hi = n;
    while (lo < hi) {
        int mid = (lo + hi) >> 1;
        if (a[mid] < v) lo = mid + 1; else hi = mid;
    }
    return lo;
}

// ---------- K1: CSR pointers + inv_deg in one kernel ----------
__global__ void build_ptrs(const int* __restrict__ dst, const int* __restrict__ batch,
                           int* __restrict__ row_ptr, int* __restrict__ graph_ptr,
                           float* __restrict__ inv_deg) {
    int i = blockIdx.x * blockDim.x + threadIdx.x;
    if (i <= N_NODES) {
        int lb = lower_bound_i(dst, N_EDGES, i);
        row_ptr[i] = lb;
        if (i < N_NODES) {
            int ub = lower_bound_i(dst, N_EDGES, i + 1);
            int cnt = ub - lb;
            inv_deg[i] = (cnt > 0) ? (1.0f / (float)cnt) : 0.0f;
        }
    }
    if (i <= N_GRAPHS) graph_ptr[i] = lower_bound_i(batch, N_NODES, i);
}

// ---------- K2: f32 -> bf16 elementwise convert (x -> xb), 4 elems/thread ----------
__global__ void convert_bf16(const float* __restrict__ S, unsigned short* __restrict__ D) {
    int i = blockIdx.x * blockDim.x + threadIdx.x;   // element group of 4
    float4 v = *(const float4*)(S + ((size_t)i << 2));
    ushort4 o;
    o.x = f2bf(v.x); o.y = f2bf(v.y); o.z = f2bf(v.z); o.w = f2bf(v.w);
    *(ushort4*)(D + ((size_t)i << 2)) = o;
}

// ---------- K3: transpose + convert all four 256x256 f32 weights -> N-major bf16 ----------
__global__ void transpose256x4(const float* __restrict__ S0, const float* __restrict__ S1,
                               const float* __restrict__ S2, const float* __restrict__ S3,
                               unsigned short* __restrict__ D0, unsigned short* __restrict__ D1,
                               unsigned short* __restrict__ D2, unsigned short* __restrict__ D3) {
    const float* S; unsigned short* D;
    switch (blockIdx.y) {
        case 0: S = S0; D = D0; break;
        case 1: S = S1; D = D1; break;
        case 2: S = S2; D = D2; break;
        default: S = S3; D = D3; break;
    }
    int i = blockIdx.x * 256 + threadIdx.x;   // i = k*256 + n
    int k = i >> 8, n = i & 255;
    D[n * 256 + k] = f2bf(S[i]);
}

// ---------- K4: mean aggregation (bf16 in/out, f32 accum) ----------
// one wave per node, lane = 4 channels (8B loads). Uniform clamped bursts:
// always 16 (or 8) gathers in flight, indices clamped, wave-uniform 0/1 weights.
__global__ void aggregate(const unsigned short* __restrict__ X,
                          const int* __restrict__ src,
                          const int* __restrict__ row_ptr,
                          const float* __restrict__ inv_deg,
                          unsigned short* __restrict__ out) {
    int gw   = (blockIdx.x * blockDim.x + threadIdx.x) >> 6;
    int lane = threadIdx.x & 63;
    if (gw >= N_NODES) return;
    int e0 = row_ptr[gw], e1 = row_ptr[gw + 1];
    const int lo = lane << 2;
    float a0 = 0.f, a1 = 0.f, a2 = 0.f, a3 = 0.f;
    int e = e0;

    // full bursts of 16 independent gathers
    for (; e + 16 <= e1; e += 16) {
        ushort4 v[16];
#pragma unroll
        for (int j = 0; j < 16; ++j) {
            int s = src[e + j];
            v[j] = *(const ushort4*)(X + ((size_t)s << 8) + lo);
        }
#pragma unroll
        for (int j = 0; j < 16; ++j) {
            a0 += us2f(v[j].x); a1 += us2f(v[j].y);
            a2 += us2f(v[j].z); a3 += us2f(v[j].w);
        }
    }
    int rem = e1 - e;
    if (rem > 8) {           // clamped burst of 16 (waste <= 7, all L1-hit)
        int cl = e1 - 1;
        ushort4 v[16]; float w[16];
#pragma unroll
        for (int j = 0; j < 16; ++j) {
            int ej = e + j;
            int ec = ej < cl ? ej : cl;
            w[j] = (ej < e1) ? 1.0f : 0.0f;
            int s = src[ec];
            v[j] = *(const ushort4*)(X + ((size_t)s << 8) + lo);
        }
#pragma unroll
        for (int j = 0; j < 16; ++j) {
            a0 = fmaf(us2f(v[j].x), w[j], a0);
            a1 = fmaf(us2f(v[j].y), w[j], a1);
            a2 = fmaf(us2f(v[j].z), w[j], a2);
            a3 = fmaf(us2f(v[j].w), w[j], a3);
        }
    } else if (rem > 0) {    // clamped burst of 8
        int cl = e1 - 1;
        ushort4 v[8]; float w[8];
#pragma unroll
        for (int j = 0; j < 8; ++j) {
            int ej = e + j;
            int ec = ej < cl ? ej : cl;
            w[j] = (ej < e1) ? 1.0f : 0.0f;
            int s = src[ec];
            v[j] = *(const ushort4*)(X + ((size_t)s << 8) + lo);
        }
#pragma unroll
        for (int j = 0; j < 8; ++j) {
            a0 = fmaf(us2f(v[j].x), w[j], a0);
            a1 = fmaf(us2f(v[j].y), w[j], a1);
            a2 = fmaf(us2f(v[j].z), w[j], a2);
            a3 = fmaf(us2f(v[j].w), w[j], a3);
        }
    }

    float sc = inv_deg[gw];
    ushort4 o;
    o.x = f2bf(a0 * sc); o.y = f2bf(a1 * sc); o.z = f2bf(a2 * sc); o.w = f2bf(a3 * sc);
    *(ushort4*)(out + ((size_t)gw << 8) + lo) = o;
}

// ---------- K5: fused SAGE GEMM: C = A1@B1 + A2@B2 + bias, optional ReLU ----------
// global_load_lds width-16 staging into unpadded [kb][row][8] LDS layout.
// Tile 128x128, 4 waves (2x2), each wave 4x4 MFMA 16x16x32. Tail rows of A
// read past M into adjacent ws slabs (valid memory); store is bounded.
__global__ __launch_bounds__(256, 2)
void gemm_fused(const unsigned short* __restrict__ A1,
                const unsigned short* __restrict__ A2,
                const unsigned short* __restrict__ B1t,
                const unsigned short* __restrict__ B2t,
                const float* __restrict__ bias,
                unsigned short* __restrict__ C,
                int M, int do_relu) {
    __shared__ __align__(16) unsigned short As[4096];  // [kb 0..3][row 0..127][8]
    __shared__ __align__(16) unsigned short Bs[4096];

    const int t    = threadIdx.x;
    const int m0   = blockIdx.x * 128;
    const int n0   = blockIdx.y * 128;
    const int lane = t & 63, wid = t >> 6;
    const int wm   = (wid >> 1) * 64;       // wave row offset in tile
    const int wn   = (wid & 1) * 64;        // wave col offset in tile
    const int lrow = lane & 15;
    const int kq   = lane >> 4;             // 0..3 -> which 8-k slice

    const f32x4 zero4 = {0.f, 0.f, 0.f, 0.f};
    f32x4 acc[4][4];
#pragma unroll
    for (int i = 0; i < 4; ++i)
#pragma unroll
        for (int j = 0; j < 4; ++j) acc[i][j] = zero4;

    for (int it = 0; it < 16; ++it) {       // K = 512 virtual (2 x 256)
        int kt = it * 32;
        const unsigned short* __restrict__ Ab = (kt < 256) ? A1 : A2;
        const unsigned short* __restrict__ Bb = (kt < 256) ? B1t : B2t;
        int ko = kt & 255;

        // async stage: 2 x 16B chunks per thread per matrix
#pragma unroll
        for (int i = 0; i < 2; ++i) {
            int q   = t + i * 256;          // chunk id 0..511
            int row = q & 127;
            int kb  = q >> 7;               // 0..3
            const unsigned short* ga = Ab + (size_t)(m0 + row) * 256 + ko + kb * 8;
            __builtin_amdgcn_global_load_lds((gu32*)ga, (lu32*)(As + q * 8), 16, 0, 0);
            const unsigned short* gb = Bb + (size_t)(n0 + row) * 256 + ko + kb * 8;
            __builtin_amdgcn_global_load_lds((gu32*)gb, (lu32*)(Bs + q * 8), 16, 0, 0);
        }
        __syncthreads();

        bf16x8 af[4], bfr[4];
#pragma unroll
        for (int mi = 0; mi < 4; ++mi) {
            uint4 u = *(const uint4*)(As + ((kq * 128) + wm + mi * 16 + lrow) * 8);
            af[mi] = __builtin_bit_cast(bf16x8, u);
        }
#pragma unroll
        for (int ni = 0; ni < 4; ++ni) {
            uint4 u = *(const uint4*)(Bs + ((kq * 128) + wn + ni * 16 + lrow) * 8);
            bfr[ni] = __builtin_bit_cast(bf16x8, u);
        }
#pragma unroll
        for (int mi = 0; mi < 4; ++mi)
#pragma unroll
            for (int ni = 0; ni < 4; ++ni)
                acc[mi][ni] = __builtin_amdgcn_mfma_f32_16x16x32_bf16(
                    af[mi], bfr[ni], acc[mi][ni], 0, 0, 0);
        __syncthreads();
    }

    // epilogue: D mapping col = lane&15, row = (lane>>4)*4 + reg
    const int rbase = (lane >> 4) * 4;
#pragma unroll
    for (int ni = 0; ni < 4; ++ni) {
        int n  = n0 + wn + ni * 16 + lrow;
        float bv = bias[n];
#pragma unroll
        for (int mi = 0; mi < 4; ++mi) {
            int mb = m0 + wm + mi * 16 + rbase;
#pragma unroll
            for (int r = 0; r < 4; ++r) {
                int m = mb + r;
                if (m < M) {
                    float v = acc[mi][ni][r] + bv;
                    if (do_relu) v = fmaxf(v, 0.f);
                    C[(size_t)m * 256 + n] = f2bf(v);
                }
            }
        }
    }
}

// ---------- K6: per-graph p-weighted mean pool + root gather -> feat[G][512] f32 ----------
// unroll-8 with clamped indices + 0/p[n] weights for MLP
__global__ void pool_feat(const unsigned short* __restrict__ h2,
                          const float* __restrict__ p,
                          const int* __restrict__ graph_ptr,
                          const int* __restrict__ root_ptr,
                          float* __restrict__ feat) {
    int g = blockIdx.x;
    int c = threadIdx.x;        // 256 threads = channels
    int s = graph_ptr[g], e = graph_ptr[g + 1];
    float acc = 0.f;
    for (int n = s; n < e; n += 8) {
        int cl = e - 1;
        unsigned short v[8]; float w[8];
#pragma unroll
        for (int j = 0; j < 8; ++j) {
            int nj = n + j;
            int nc = nj < cl ? nj : cl;
            w[j] = (nj < e) ? p[nc] : 0.0f;
            v[j] = h2[(size_t)nc * 256 + c];
        }
#pragma unroll
        for (int j = 0; j < 8; ++j)
            acc = fmaf(us2f(v[j]), w[j], acc);
    }
    float cnt = (float)(e - s);
    float gmean = acc / fmaxf(cnt, 1.0f);
    int root = root_ptr[g];
    feat[(size_t)g * 512 + c]       = us2f(h2[(size_t)root * 256 + c]);
    feat[(size_t)g * 512 + 256 + c] = gmean;
}

// ---------- K7: final linear  out = feat @ Wlin + blin  (all f32) ----------
__global__ void final_gemm(const float* __restrict__ feat,
                           const float* __restrict__ Wlin,
                           const float* __restrict__ blin,
                           float* __restrict__ out) {
    int g = blockIdx.x;
    int o = threadIdx.x;        // 128 threads
    __shared__ float fl[512];
    for (int k = o; k < 512; k += 128) fl[k] = feat[(size_t)g * 512 + k];
    __syncthreads();
    float s0 = 0.f, s1 = 0.f, s2 = 0.f, s3 = 0.f;
    for (int k = 0; k < 512; k += 4) {
        s0 = fmaf(fl[k + 0], Wlin[(k + 0) * 128 + o], s0);
        s1 = fmaf(fl[k + 1], Wlin[(k + 1) * 128 + o], s1);
        s2 = fmaf(fl[k + 2], Wlin[(k + 2) * 128 + o], s2);
        s3 = fmaf(fl[k + 3], Wlin[(k + 3) * 128 + o], s3);
    }
    out[(size_t)g * 128 + o] = blin[o] + ((s0 + s1) + (s2 + s3));
}

extern "C" void kernel_launch(void* const* d_in, const int* in_sizes, int n_in,
                              void* d_out, int out_size, void* d_ws, size_t ws_size,
                              hipStream_t stream) {
    // inputs: all float arrays are f32 (per the reference), ints are int32
    const float* x        = (const float*)d_in[0];
    const int*   src      = (const int*)d_in[1];
    const int*   dst      = (const int*)d_in[2];
    const float* p        = (const float*)d_in[3];
    const int*   batch    = (const int*)d_in[4];
    const int*   root_ptr = (const int*)d_in[5];
    // d_in[6] = num_graphs (256, hard-coded)
    const float* Wl1  = (const float*)d_in[7];
    const float* Wr1  = (const float*)d_in[8];
    const float* b1   = (const float*)d_in[9];
    const float* Wl2  = (const float*)d_in[10];
    const float* Wr2  = (const float*)d_in[11];
    const float* b2   = (const float*)d_in[12];
    const float* Wlin = (const float*)d_in[13];
    const float* blin = (const float*)d_in[14];
    float* out = (float*)d_out;

    // workspace layout (256B aligned slabs)
    size_t off = 0;
    char* base = (char*)d_ws;
    auto alloc = [&](size_t bytes) -> void* {
        void* q = base + off;
        off += (bytes + 255) & ~(size_t)255;
        return q;
    };
    int*            row_ptr   = (int*)  alloc((N_NODES + 1) * sizeof(int));
    int*            graph_ptr = (int*)  alloc((N_GRAPHS + 1) * sizeof(int));
    float*          inv_deg   = (float*)alloc(N_NODES * sizeof(float));
    unsigned short* Wl1t = (unsigned short*)alloc(256 * 256 * 2);
    unsigned short* Wr1t = (unsigned short*)alloc(256 * 256 * 2);
    unsigned short* Wl2t = (unsigned short*)alloc(256 * 256 * 2);
    unsigned short* Wr2t = (unsigned short*)alloc(256 * 256 * 2);
    unsigned short* xb   = (unsigned short*)alloc((size_t)N_NODES * 256 * 2);
    unsigned short* aggb = (unsigned short*)alloc((size_t)N_NODES * 256 * 2);
    unsigned short* h1   = (unsigned short*)alloc((size_t)N_NODES * 256 * 2);
    unsigned short* h2   = (unsigned short*)alloc((size_t)N_NODES * 256 * 2);
    float*          feat = (float*)alloc((size_t)N_GRAPHS * 512 * sizeof(float));
    (void)ws_size; (void)n_in; (void)in_sizes; (void)out_size;

    build_ptrs<<<196, 256, 0, stream>>>(dst, batch, row_ptr, graph_ptr, inv_deg);
    convert_bf16<<<N_NODES * 256 / 4 / 256, 256, 0, stream>>>(x, xb);
    transpose256x4<<<dim3(256, 4), 256, 0, stream>>>(Wl1, Wr1, Wl2, Wr2,
                                                     Wl1t, Wr1t, Wl2t, Wr2t);

    dim3 ggrid((N_NODES + 127) / 128, 2);

    // conv1: h1 = relu(agg(x)@Wl1 + x@Wr1 + b1)
    aggregate<<<N_NODES / 4, 256, 0, stream>>>(xb, src, row_ptr, inv_deg, aggb);
    gemm_fused<<<ggrid, 256, 0, stream>>>(aggb, xb, Wl1t, Wr1t, b1, h1, N_NODES, 1);

    // conv2: h2 = agg(h1)@Wl2 + h1@Wr2 + b2
    aggregate<<<N_NODES / 4, 256, 0, stream>>>(h1, src, row_ptr, inv_deg, aggb);
    gemm_fused<<<ggrid, 256, 0, stream>>>(aggb, h1, Wl2t, Wr2t, b2, h2, N_NODES, 0);

    // pool + root gather + final linear
    pool_feat<<<N_GRAPHS, 256, 0, stream>>>(h2, p, graph_ptr, root_ptr, feat);
    final_gemm<<<N_GRAPHS, 128, 0, stream>>>(feat, Wlin, blin, out);
}

// Round 5
// 345.741 us; speedup vs baseline: 1.3413x; 1.1009x over previous
//
#include <hip/hip_runtime.h>
#include <hip/hip_bf16.h>

// ---------- problem constants ----------
#define N_NODES 50000
#define N_EDGES 800000
#define C_DIM   256      // IN_C == HID_C
#define OUT_C   128
#define N_GRAPHS 256

typedef unsigned short ushort8 __attribute__((ext_vector_type(8)));
typedef __bf16         bf16x8  __attribute__((ext_vector_type(8)));
typedef float          f32x4   __attribute__((ext_vector_type(4)));

typedef __attribute__((address_space(1))) const unsigned int gu32;
typedef __attribute__((address_space(3))) unsigned int lu32;

#if __has_builtin(__builtin_amdgcn_sched_barrier)
#define SCHED_FENCE() __builtin_amdgcn_sched_barrier(0)
#else
#define SCHED_FENCE() ((void)0)
#endif

__device__ __forceinline__ float us2f(unsigned short u) {
    unsigned int x = ((unsigned int)u) << 16;
    return __builtin_bit_cast(float, x);
}
__device__ __forceinline__ unsigned short f2bf(float f) {
    unsigned int u = __builtin_bit_cast(unsigned int, f);
    u += 0x7fffu + ((u >> 16) & 1u);   // RNE
    return (unsigned short)(u >> 16);
}

__device__ __forceinline__ int lower_bound_i(const int* __restrict__ a, int n, int v) {
    int lo = 0, hi = n;
    while (lo < hi) {
        int mid = (lo + hi) >> 1;
        if (a[mid] < v) lo = mid + 1; else hi = mid;
    }
    return lo;
}

// ---------- K1: CSR pointers + inv_deg in one kernel ----------
__global__ void build_ptrs(const int* __restrict__ dst, const int* __restrict__ batch,
                           int* __restrict__ row_ptr, int* __restrict__ graph_ptr,
                           float* __restrict__ inv_deg) {
    int i = blockIdx.x * blockDim.x + threadIdx.x;
    if (i <= N_NODES) {
        int lb = lower_bound_i(dst, N_EDGES, i);
        row_ptr[i] = lb;
        if (i < N_NODES) {
            int ub = lower_bound_i(dst, N_EDGES, i + 1);
            int cnt = ub - lb;
            inv_deg[i] = (cnt > 0) ? (1.0f / (float)cnt) : 0.0f;
        }
    }
    if (i <= N_GRAPHS) graph_ptr[i] = lower_bound_i(batch, N_NODES, i);
}

// ---------- K2: f32 -> bf16 elementwise convert (x -> xb), 4 elems/thread ----------
__global__ void convert_bf16(const float* __restrict__ S, unsigned short* __restrict__ D) {
    int i = blockIdx.x * blockDim.x + threadIdx.x;   // element group of 4
    float4 v = *(const float4*)(S + ((size_t)i << 2));
    ushort4 o;
    o.x = f2bf(v.x); o.y = f2bf(v.y); o.z = f2bf(v.z); o.w = f2bf(v.w);
    *(ushort4*)(D + ((size_t)i << 2)) = o;
}

// ---------- K3: transpose + convert all four 256x256 f32 weights -> N-major bf16 ----------
__global__ void transpose256x4(const float* __restrict__ S0, const float* __restrict__ S1,
                               const float* __restrict__ S2, const float* __restrict__ S3,
                               unsigned short* __restrict__ D0, unsigned short* __restrict__ D1,
                               unsigned short* __restrict__ D2, unsigned short* __restrict__ D3) {
    const float* S; unsigned short* D;
    switch (blockIdx.y) {
        case 0: S = S0; D = D0; break;
        case 1: S = S1; D = D1; break;
        case 2: S = S2; D = D2; break;
        default: S = S3; D = D3; break;
    }
    int i = blockIdx.x * 256 + threadIdx.x;   // i = k*256 + n
    int k = i >> 8, n = i & 255;
    D[n * 256 + k] = f2bf(S[i]);
}

// ---------- K4: mean aggregation (bf16 in/out, f32 accum) ----------
// one wave per node, lane = 4 channels (8B loads). Bursts of 16 gathers with a
// sched_barrier fence so the compiler cannot collapse them (round-4: VGPR=24
// proved the burst was serialized; fence forces ~16 outstanding loads).
__global__ void aggregate(const unsigned short* __restrict__ X,
                          const int* __restrict__ src,
                          const int* __restrict__ row_ptr,
                          const float* __restrict__ inv_deg,
                          unsigned short* __restrict__ out) {
    int gw   = (blockIdx.x * blockDim.x + threadIdx.x) >> 6;
    int lane = threadIdx.x & 63;
    if (gw >= N_NODES) return;
    int e0 = row_ptr[gw], e1 = row_ptr[gw + 1];
    const int lo = lane << 2;
    float a0 = 0.f, a1 = 0.f, a2 = 0.f, a3 = 0.f;
    int e = e0;

    for (; e + 16 <= e1; e += 16) {
        int sidx[16];
#pragma unroll
        for (int j = 0; j < 16; ++j) sidx[j] = src[e + j];
        ushort4 v[16];
#pragma unroll
        for (int j = 0; j < 16; ++j)
            v[j] = *(const ushort4*)(X + ((size_t)sidx[j] << 8) + lo);
        SCHED_FENCE();
#pragma unroll
        for (int j = 0; j < 16; ++j) {
            a0 += us2f(v[j].x); a1 += us2f(v[j].y);
            a2 += us2f(v[j].z); a3 += us2f(v[j].w);
        }
    }
    int rem = e1 - e;
    if (rem > 0) {           // clamped burst of 16 (waste <= 15, all L1/L2-hit)
        int cl = e1 - 1;
        int sidx[16]; float w[16];
#pragma unroll
        for (int j = 0; j < 16; ++j) {
            int ej = e + j;
            int ec = ej < cl ? ej : cl;
            w[j] = (ej < e1) ? 1.0f : 0.0f;
            sidx[j] = src[ec];
        }
        ushort4 v[16];
#pragma unroll
        for (int j = 0; j < 16; ++j)
            v[j] = *(const ushort4*)(X + ((size_t)sidx[j] << 8) + lo);
        SCHED_FENCE();
#pragma unroll
        for (int j = 0; j < 16; ++j) {
            a0 = fmaf(us2f(v[j].x), w[j], a0);
            a1 = fmaf(us2f(v[j].y), w[j], a1);
            a2 = fmaf(us2f(v[j].z), w[j], a2);
            a3 = fmaf(us2f(v[j].w), w[j], a3);
        }
    }

    float sc = inv_deg[gw];
    ushort4 o;
    o.x = f2bf(a0 * sc); o.y = f2bf(a1 * sc); o.z = f2bf(a2 * sc); o.w = f2bf(a3 * sc);
    *(ushort4*)(out + ((size_t)gw << 8) + lo) = o;
}

// ---------- K5: fused SAGE GEMM: C = A1@B1 + A2@B2 + bias, optional ReLU ----------
// BK=64 (8 iters, half the barrier drains). Staging via global_load_lds w=16
// with row-major chunks: 8 consecutive lanes cover one row's 128B (full 64B
// lines), LDS slot = row*8 + (kb ^ (row&7)) — XOR involution keeps the
// lane-contiguous LDS constraint AND makes fragment ds_read_b128 banks spread
// across all 32 banks at 2-way (free). Tail rows read past M into adjacent ws
// slabs (valid memory); store is bounded.
__global__ __launch_bounds__(256, 2)
void gemm_fused(const unsigned short* __restrict__ A1,
                const unsigned short* __restrict__ A2,
                const unsigned short* __restrict__ B1t,
                const unsigned short* __restrict__ B2t,
                const float* __restrict__ bias,
                unsigned short* __restrict__ C,
                int M, int do_relu) {
    __shared__ __align__(16) unsigned short As[8192];  // 128 rows x 8 chunks x 8 shorts
    __shared__ __align__(16) unsigned short Bs[8192];

    const int t    = threadIdx.x;
    const int m0   = blockIdx.x * 128;
    const int n0   = blockIdx.y * 128;
    const int lane = t & 63, wid = t >> 6;
    const int wm   = (wid >> 1) * 64;       // wave row offset in tile
    const int wn   = (wid & 1) * 64;        // wave col offset in tile
    const int lrow = lane & 15;
    const int kq   = lane >> 4;             // 0..3 -> which 8-k slice of the 32-k step

    const f32x4 zero4 = {0.f, 0.f, 0.f, 0.f};
    f32x4 acc[4][4];
#pragma unroll
    for (int i = 0; i < 4; ++i)
#pragma unroll
        for (int j = 0; j < 4; ++j) acc[i][j] = zero4;

    for (int it = 0; it < 8; ++it) {        // K = 512 virtual (2 x 256), BK = 64
        const unsigned short* __restrict__ Ab = (it < 4) ? A1 : A2;
        const unsigned short* __restrict__ Bb = (it < 4) ? B1t : B2t;
        int ko = (it * 64) & 255;

        // async stage: 4 x 16B chunks per thread per matrix
#pragma unroll
        for (int i = 0; i < 4; ++i) {
            int q   = t + i * 256;          // LDS slot 0..1023
            int row = q >> 3;
            int kb  = (q & 7) ^ (row & 7);  // global chunk this slot holds
            const unsigned short* ga = Ab + (size_t)(m0 + row) * 256 + ko + kb * 8;
            __builtin_amdgcn_global_load_lds((gu32*)ga, (lu32*)(As + q * 8), 16, 0, 0);
            const unsigned short* gb = Bb + (size_t)(n0 + row) * 256 + ko + kb * 8;
            __builtin_amdgcn_global_load_lds((gu32*)gb, (lu32*)(Bs + q * 8), 16, 0, 0);
        }
        __syncthreads();

#pragma unroll
        for (int s = 0; s < 2; ++s) {       // two 32-k MFMA steps per BK=64
            int kqp = s * 4 + kq;
            bf16x8 af[4], bfr[4];
#pragma unroll
            for (int mi = 0; mi < 4; ++mi) {
                int r = wm + mi * 16 + lrow;
                int slot = r * 8 + (kqp ^ (lrow & 7));
                uint4 u = *(const uint4*)(As + slot * 8);
                af[mi] = __builtin_bit_cast(bf16x8, u);
            }
#pragma unroll
            for (int ni = 0; ni < 4; ++ni) {
                int r = wn + ni * 16 + lrow;
                int slot = r * 8 + (kqp ^ (lrow & 7));
                uint4 u = *(const uint4*)(Bs + slot * 8);
                bfr[ni] = __builtin_bit_cast(bf16x8, u);
            }
#pragma unroll
            for (int mi = 0; mi < 4; ++mi)
#pragma unroll
                for (int ni = 0; ni < 4; ++ni)
                    acc[mi][ni] = __builtin_amdgcn_mfma_f32_16x16x32_bf16(
                        af[mi], bfr[ni], acc[mi][ni], 0, 0, 0);
        }
        __syncthreads();
    }

    // epilogue: D mapping col = lane&15, row = (lane>>4)*4 + reg
    const int rbase = (lane >> 4) * 4;
#pragma unroll
    for (int ni = 0; ni < 4; ++ni) {
        int n  = n0 + wn + ni * 16 + lrow;
        float bv = bias[n];
#pragma unroll
        for (int mi = 0; mi < 4; ++mi) {
            int mb = m0 + wm + mi * 16 + rbase;
#pragma unroll
            for (int r = 0; r < 4; ++r) {
                int m = mb + r;
                if (m < M) {
                    float v = acc[mi][ni][r] + bv;
                    if (do_relu) v = fmaxf(v, 0.f);
                    C[(size_t)m * 256 + n] = f2bf(v);
                }
            }
        }
    }
}

// ---------- K6: per-graph p-weighted mean pool + root gather -> feat[G][512] f32 ----------
__global__ void pool_feat(const unsigned short* __restrict__ h2,
                          const float* __restrict__ p,
                          const int* __restrict__ graph_ptr,
                          const int* __restrict__ root_ptr,
                          float* __restrict__ feat) {
    int g = blockIdx.x;
    int c = threadIdx.x;        // 256 threads = channels
    int s = graph_ptr[g], e = graph_ptr[g + 1];
    float acc = 0.f;
    for (int n = s; n < e; n += 8) {
        int cl = e - 1;
        float w[8]; int nc[8];
#pragma unroll
        for (int j = 0; j < 8; ++j) {
            int nj = n + j;
            nc[j] = nj < cl ? nj : cl;
            w[j] = (nj < e) ? p[nc[j]] : 0.0f;
        }
        unsigned short v[8];
#pragma unroll
        for (int j = 0; j < 8; ++j)
            v[j] = h2[(size_t)nc[j] * 256 + c];
        SCHED_FENCE();
#pragma unroll
        for (int j = 0; j < 8; ++j)
            acc = fmaf(us2f(v[j]), w[j], acc);
    }
    float cnt = (float)(e - s);
    float gmean = acc / fmaxf(cnt, 1.0f);
    int root = root_ptr[g];
    feat[(size_t)g * 512 + c]       = us2f(h2[(size_t)root * 256 + c]);
    feat[(size_t)g * 512 + 256 + c] = gmean;
}

// ---------- K7: final linear  out = feat @ Wlin + blin  (all f32) ----------
__global__ void final_gemm(const float* __restrict__ feat,
                           const float* __restrict__ Wlin,
                           const float* __restrict__ blin,
                           float* __restrict__ out) {
    int g = blockIdx.x;
    int o = threadIdx.x;        // 128 threads
    __shared__ float fl[512];
    for (int k = o; k < 512; k += 128) fl[k] = feat[(size_t)g * 512 + k];
    __syncthreads();
    float s0 = 0.f, s1 = 0.f, s2 = 0.f, s3 = 0.f;
    for (int k = 0; k < 512; k += 4) {
        s0 = fmaf(fl[k + 0], Wlin[(k + 0) * 128 + o], s0);
        s1 = fmaf(fl[k + 1], Wlin[(k + 1) * 128 + o], s1);
        s2 = fmaf(fl[k + 2], Wlin[(k + 2) * 128 + o], s2);
        s3 = fmaf(fl[k + 3], Wlin[(k + 3) * 128 + o], s3);
    }
    out[(size_t)g * 128 + o] = blin[o] + ((s0 + s1) + (s2 + s3));
}

extern "C" void kernel_launch(void* const* d_in, const int* in_sizes, int n_in,
                              void* d_out, int out_size, void* d_ws, size_t ws_size,
                              hipStream_t stream) {
    // inputs: all float arrays are f32 (per the reference), ints are int32
    const float* x        = (const float*)d_in[0];
    const int*   src      = (const int*)d_in[1];
    const int*   dst      = (const int*)d_in[2];
    const float* p        = (const float*)d_in[3];
    const int*   batch    = (const int*)d_in[4];
    const int*   root_ptr = (const int*)d_in[5];
    // d_in[6] = num_graphs (256, hard-coded)
    const float* Wl1  = (const float*)d_in[7];
    const float* Wr1  = (const float*)d_in[8];
    const float* b1   = (const float*)d_in[9];
    const float* Wl2  = (const float*)d_in[10];
    const float* Wr2  = (const float*)d_in[11];
    const float* b2   = (const float*)d_in[12];
    const float* Wlin = (const float*)d_in[13];
    const float* blin = (const float*)d_in[14];
    float* out = (float*)d_out;

    // workspace layout (256B aligned slabs)
    size_t off = 0;
    char* base = (char*)d_ws;
    auto alloc = [&](size_t bytes) -> void* {
        void* q = base + off;
        off += (bytes + 255) & ~(size_t)255;
        return q;
    };
    int*            row_ptr   = (int*)  alloc((N_NODES + 1) * sizeof(int));
    int*            graph_ptr = (int*)  alloc((N_GRAPHS + 1) * sizeof(int));
    float*          inv_deg   = (float*)alloc(N_NODES * sizeof(float));
    unsigned short* Wl1t = (unsigned short*)alloc(256 * 256 * 2);
    unsigned short* Wr1t = (unsigned short*)alloc(256 * 256 * 2);
    unsigned short* Wl2t = (unsigned short*)alloc(256 * 256 * 2);
    unsigned short* Wr2t = (unsigned short*)alloc(256 * 256 * 2);
    unsigned short* xb   = (unsigned short*)alloc((size_t)N_NODES * 256 * 2);
    unsigned short* aggb = (unsigned short*)alloc((size_t)N_NODES * 256 * 2);
    unsigned short* h1   = (unsigned short*)alloc((size_t)N_NODES * 256 * 2);
    unsigned short* h2   = (unsigned short*)alloc((size_t)N_NODES * 256 * 2);
    float*          feat = (float*)alloc((size_t)N_GRAPHS * 512 * sizeof(float));
    (void)ws_size; (void)n_in; (void)in_sizes; (void)out_size;

    build_ptrs<<<196, 256, 0, stream>>>(dst, batch, row_ptr, graph_ptr, inv_deg);
    convert_bf16<<<N_NODES * 256 / 4 / 256, 256, 0, stream>>>(x, xb);
    transpose256x4<<<dim3(256, 4), 256, 0, stream>>>(Wl1, Wr1, Wl2, Wr2,
                                                     Wl1t, Wr1t, Wl2t, Wr2t);

    dim3 ggrid((N_NODES + 127) / 128, 2);

    // conv1: h1 = relu(agg(x)@Wl1 + x@Wr1 + b1)
    aggregate<<<N_NODES / 4, 256, 0, stream>>>(xb, src, row_ptr, inv_deg, aggb);
    gemm_fused<<<ggrid, 256, 0, stream>>>(aggb, xb, Wl1t, Wr1t, b1, h1, N_NODES, 1);

    // conv2: h2 = agg(h1)@Wl2 + h1@Wr2 + b2
    aggregate<<<N_NODES / 4, 256, 0, stream>>>(h1, src, row_ptr, inv_deg, aggb);
    gemm_fused<<<ggrid, 256, 0, stream>>>(aggb, h1, Wl2t, Wr2t, b2, h2, N_NODES, 0);

    // pool + root gather + final linear
    pool_feat<<<N_GRAPHS, 256, 0, stream>>>(h2, p, graph_ptr, root_ptr, feat);
    final_gemm<<<N_GRAPHS, 128, 0, stream>>>(feat, Wlin, blin, out);
}

// Round 6
// 327.071 us; speedup vs baseline: 1.4179x; 1.0571x over previous
//
#include <hip/hip_runtime.h>
#include <hip/hip_bf16.h>

// ---------- problem constants ----------
#define N_NODES 50000
#define N_EDGES 800000
#define C_DIM   256      // IN_C == HID_C
#define OUT_C   128
#define N_GRAPHS 256

typedef unsigned short ushort8 __attribute__((ext_vector_type(8)));
typedef __bf16         bf16x8  __attribute__((ext_vector_type(8)));
typedef float          f32x4   __attribute__((ext_vector_type(4)));

typedef __attribute__((address_space(1))) const unsigned int gu32;
typedef __attribute__((address_space(3))) unsigned int lu32;

#if __has_builtin(__builtin_amdgcn_sched_barrier)
#define SCHED_FENCE() __builtin_amdgcn_sched_barrier(0)
#else
#define SCHED_FENCE() ((void)0)
#endif

__device__ __forceinline__ float us2f(unsigned short u) {
    unsigned int x = ((unsigned int)u) << 16;
    return __builtin_bit_cast(float, x);
}
__device__ __forceinline__ unsigned short f2bf(float f) {
    unsigned int u = __builtin_bit_cast(unsigned int, f);
    u += 0x7fffu + ((u >> 16) & 1u);   // RNE
    return (unsigned short)(u >> 16);
}

__device__ __forceinline__ int lower_bound_i(const int* __restrict__ a, int n, int v) {
    int lo = 0, hi = n;
    while (lo < hi) {
        int mid = (lo + hi) >> 1;
        if (a[mid] < v) lo = mid + 1; else hi = mid;
    }
    return lo;
}

// ---------- K1: merged preprocess ----------
// blocks [0,12500): convert x f32->bf16 (4 elems/thread)
// blocks [12500,13524): transpose+convert 4 weights
// blocks [13524,13720): CSR row_ptr/graph_ptr/inv_deg
__global__ void preprocess(const float* __restrict__ x, unsigned short* __restrict__ xb,
                           const float* __restrict__ W0, const float* __restrict__ W1,
                           const float* __restrict__ W2, const float* __restrict__ W3,
                           unsigned short* __restrict__ D0, unsigned short* __restrict__ D1,
                           unsigned short* __restrict__ D2, unsigned short* __restrict__ D3,
                           const int* __restrict__ dst, const int* __restrict__ batch,
                           int* __restrict__ row_ptr, int* __restrict__ graph_ptr,
                           float* __restrict__ inv_deg) {
    int b = blockIdx.x;
    int t = threadIdx.x;
    if (b < 12500) {
        int i = b * 256 + t;                 // group of 4 elements
        float4 v = *(const float4*)(x + ((size_t)i << 2));
        ushort4 o;
        o.x = f2bf(v.x); o.y = f2bf(v.y); o.z = f2bf(v.z); o.w = f2bf(v.w);
        *(ushort4*)(xb + ((size_t)i << 2)) = o;
    } else if (b < 13524) {
        int sub = b - 12500;
        const float* S; unsigned short* D;
        switch (sub >> 8) {
            case 0: S = W0; D = D0; break;
            case 1: S = W1; D = D1; break;
            case 2: S = W2; D = D2; break;
            default: S = W3; D = D3; break;
        }
        int i = (sub & 255) * 256 + t;       // i = k*256 + n
        int k = i >> 8, n = i & 255;
        D[n * 256 + k] = f2bf(S[i]);
    } else {
        int i = (b - 13524) * 256 + t;
        if (i <= N_NODES) {
            int lb = lower_bound_i(dst, N_EDGES, i);
            row_ptr[i] = lb;
            if (i < N_NODES) {
                int ub = lower_bound_i(dst, N_EDGES, i + 1);
                int cnt = ub - lb;
                inv_deg[i] = (cnt > 0) ? (1.0f / (float)cnt) : 0.0f;
            }
        }
        if (i <= N_GRAPHS) graph_ptr[i] = lower_bound_i(batch, N_NODES, i);
    }
}

// ---------- K2: mean aggregation (bf16 in/out, f32 accum) ----------
// one wave per node, lane = 4 channels. src[e] is wave-uniform -> readfirstlane
// puts the row base in SGPRs: zero VALU address math per gather. 16-deep
// bursts + sched fence keep ~16 loads outstanding.
__global__ void aggregate(const unsigned short* __restrict__ X,
                          const int* __restrict__ src,
                          const int* __restrict__ row_ptr,
                          const float* __restrict__ inv_deg,
                          unsigned short* __restrict__ out) {
    int gw   = (blockIdx.x * blockDim.x + threadIdx.x) >> 6;
    int lane = threadIdx.x & 63;
    if (gw >= N_NODES) return;
    int e0 = row_ptr[gw], e1 = row_ptr[gw + 1];
    const int lo = lane << 2;
    float a0 = 0.f, a1 = 0.f, a2 = 0.f, a3 = 0.f;
    int e = e0;

    for (; e + 16 <= e1; e += 16) {
        ushort4 v[16];
#pragma unroll
        for (int j = 0; j < 16; ++j) {
            int s = __builtin_amdgcn_readfirstlane(src[e + j]);
            v[j] = *(const ushort4*)(X + ((size_t)s << 8) + lo);
        }
        SCHED_FENCE();
#pragma unroll
        for (int j = 0; j < 16; ++j) {
            a0 += us2f(v[j].x); a1 += us2f(v[j].y);
            a2 += us2f(v[j].z); a3 += us2f(v[j].w);
        }
    }
    int rem = e1 - e;
    if (rem > 0) {           // clamped burst of 16 (extra loads hit same line)
        int cl = e1 - 1;
        ushort4 v[16]; float w[16];
#pragma unroll
        for (int j = 0; j < 16; ++j) {
            int ej = e + j;
            int ec = ej < cl ? ej : cl;
            w[j] = (ej < e1) ? 1.0f : 0.0f;
            int s = __builtin_amdgcn_readfirstlane(src[ec]);
            v[j] = *(const ushort4*)(X + ((size_t)s << 8) + lo);
        }
        SCHED_FENCE();
#pragma unroll
        for (int j = 0; j < 16; ++j) {
            a0 = fmaf(us2f(v[j].x), w[j], a0);
            a1 = fmaf(us2f(v[j].y), w[j], a1);
            a2 = fmaf(us2f(v[j].z), w[j], a2);
            a3 = fmaf(us2f(v[j].w), w[j], a3);
        }
    }

    float sc = inv_deg[gw];
    ushort4 o;
    o.x = f2bf(a0 * sc); o.y = f2bf(a1 * sc); o.z = f2bf(a2 * sc); o.w = f2bf(a3 * sc);
    *(ushort4*)(out + ((size_t)gw << 8) + lo) = o;
}

// ---------- K3: fused SAGE GEMM: C = A1@B1 + A2@B2 + bias, optional ReLU ----------
// One block = 128-row strip x FULL N=256 (A rows read once, not twice).
// 512 threads = 8 waves (2m x 4n), each wave 4x4 MFMA 16x16x32, BK=64.
// global_load_lds w=16, row-major chunks (8 lanes = one row's 128B, full 64B
// lines), LDS slot = row*8 + (kb ^ (row&7)) XOR swizzle (bank-spread, and
// involution keeps the lane-contiguous LDS constraint). Tail rows read past M
// into adjacent ws slabs (valid memory); store is bounded.
__global__ __launch_bounds__(512, 2)
void gemm_fused(const unsigned short* __restrict__ A1,
                const unsigned short* __restrict__ A2,
                const unsigned short* __restrict__ B1t,
                const unsigned short* __restrict__ B2t,
                const float* __restrict__ bias,
                unsigned short* __restrict__ C,
                int M, int do_relu) {
    __shared__ __align__(16) unsigned short As[8192];   // 128 rows x 8 chunks x 8
    __shared__ __align__(16) unsigned short Bs[16384];  // 256 rows x 8 chunks x 8

    const int t    = threadIdx.x;
    const int m0   = blockIdx.x * 128;
    const int lane = t & 63, wid = t >> 6;
    const int wm   = (wid >> 2) * 64;       // {0,64}
    const int wn   = (wid & 3) * 64;        // {0,64,128,192}
    const int lrow = lane & 15;
    const int kq   = lane >> 4;             // 0..3

    const f32x4 zero4 = {0.f, 0.f, 0.f, 0.f};
    f32x4 acc[4][4];
#pragma unroll
    for (int i = 0; i < 4; ++i)
#pragma unroll
        for (int j = 0; j < 4; ++j) acc[i][j] = zero4;

    for (int it = 0; it < 8; ++it) {        // K = 512 virtual (2 x 256), BK = 64
        const unsigned short* __restrict__ Ab = (it < 4) ? A1 : A2;
        const unsigned short* __restrict__ Bb = (it < 4) ? B1t : B2t;
        int ko = (it * 64) & 255;

        // stage A: 2 x 16B per thread; B: 4 x 16B per thread
#pragma unroll
        for (int i = 0; i < 2; ++i) {
            int q   = t + i * 512;          // 0..1023
            int row = q >> 3;
            int kb  = (q & 7) ^ (row & 7);
            const unsigned short* ga = Ab + (size_t)(m0 + row) * 256 + ko + kb * 8;
            __builtin_amdgcn_global_load_lds((gu32*)ga, (lu32*)(As + q * 8), 16, 0, 0);
        }
#pragma unroll
        for (int i = 0; i < 4; ++i) {
            int q   = t + i * 512;          // 0..2047
            int row = q >> 3;
            int kb  = (q & 7) ^ (row & 7);
            const unsigned short* gb = Bb + (size_t)row * 256 + ko + kb * 8;
            __builtin_amdgcn_global_load_lds((gu32*)gb, (lu32*)(Bs + q * 8), 16, 0, 0);
        }
        __syncthreads();

#pragma unroll
        for (int s = 0; s < 2; ++s) {       // two 32-k MFMA steps per BK=64
            int kqp = s * 4 + kq;
            bf16x8 af[4], bfr[4];
#pragma unroll
            for (int mi = 0; mi < 4; ++mi) {
                int r = wm + mi * 16 + lrow;
                int slot = r * 8 + (kqp ^ (lrow & 7));
                uint4 u = *(const uint4*)(As + slot * 8);
                af[mi] = __builtin_bit_cast(bf16x8, u);
            }
#pragma unroll
            for (int ni = 0; ni < 4; ++ni) {
                int r = wn + ni * 16 + lrow;
                int slot = r * 8 + (kqp ^ (lrow & 7));
                uint4 u = *(const uint4*)(Bs + slot * 8);
                bfr[ni] = __builtin_bit_cast(bf16x8, u);
            }
#pragma unroll
            for (int mi = 0; mi < 4; ++mi)
#pragma unroll
                for (int ni = 0; ni < 4; ++ni)
                    acc[mi][ni] = __builtin_amdgcn_mfma_f32_16x16x32_bf16(
                        af[mi], bfr[ni], acc[mi][ni], 0, 0, 0);
        }
        __syncthreads();
    }

    // epilogue: D mapping col = lane&15, row = (lane>>4)*4 + reg
    const int rbase = (lane >> 4) * 4;
#pragma unroll
    for (int ni = 0; ni < 4; ++ni) {
        int n  = wn + ni * 16 + lrow;
        float bv = bias[n];
#pragma unroll
        for (int mi = 0; mi < 4; ++mi) {
            int mb = m0 + wm + mi * 16 + rbase;
#pragma unroll
            for (int r = 0; r < 4; ++r) {
                int m = mb + r;
                if (m < M) {
                    float v = acc[mi][ni][r] + bv;
                    if (do_relu) v = fmaxf(v, 0.f);
                    C[(size_t)m * 256 + n] = f2bf(v);
                }
            }
        }
    }
}

// ---------- K4: per-graph p-weighted mean pool + root gather -> feat[G][512] f32 ----------
__global__ void pool_feat(const unsigned short* __restrict__ h2,
                          const float* __restrict__ p,
                          const int* __restrict__ graph_ptr,
                          const int* __restrict__ root_ptr,
                          float* __restrict__ feat) {
    int g = blockIdx.x;
    int c = threadIdx.x;        // 256 threads = channels
    int s = graph_ptr[g], e = graph_ptr[g + 1];
    float acc = 0.f;
    for (int n = s; n < e; n += 8) {
        int cl = e - 1;
        float w[8]; unsigned short v[8];
#pragma unroll
        for (int j = 0; j < 8; ++j) {
            int nj = n + j;
            int ncj = nj < cl ? nj : cl;
            int nu = __builtin_amdgcn_readfirstlane(ncj);
            w[j] = (nj < e) ? p[nu] : 0.0f;
            v[j] = h2[(size_t)nu * 256 + c];
        }
        SCHED_FENCE();
#pragma unroll
        for (int j = 0; j < 8; ++j)
            acc = fmaf(us2f(v[j]), w[j], acc);
    }
    float cnt = (float)(e - s);
    float gmean = acc / fmaxf(cnt, 1.0f);
    int root = root_ptr[g];
    feat[(size_t)g * 512 + c]       = us2f(h2[(size_t)root * 256 + c]);
    feat[(size_t)g * 512 + 256 + c] = gmean;
}

// ---------- K5: final linear  out = feat @ Wlin + blin  (all f32) ----------
__global__ void final_gemm(const float* __restrict__ feat,
                           const float* __restrict__ Wlin,
                           const float* __restrict__ blin,
                           float* __restrict__ out) {
    int g = blockIdx.x;
    int o = threadIdx.x;        // 128 threads
    __shared__ float fl[512];
    for (int k = o; k < 512; k += 128) fl[k] = feat[(size_t)g * 512 + k];
    __syncthreads();
    float s0 = 0.f, s1 = 0.f, s2 = 0.f, s3 = 0.f;
    for (int k = 0; k < 512; k += 4) {
        s0 = fmaf(fl[k + 0], Wlin[(k + 0) * 128 + o], s0);
        s1 = fmaf(fl[k + 1], Wlin[(k + 1) * 128 + o], s1);
        s2 = fmaf(fl[k + 2], Wlin[(k + 2) * 128 + o], s2);
        s3 = fmaf(fl[k + 3], Wlin[(k + 3) * 128 + o], s3);
    }
    out[(size_t)g * 128 + o] = blin[o] + ((s0 + s1) + (s2 + s3));
}

extern "C" void kernel_launch(void* const* d_in, const int* in_sizes, int n_in,
                              void* d_out, int out_size, void* d_ws, size_t ws_size,
                              hipStream_t stream) {
    // inputs: all float arrays are f32 (per the reference), ints are int32
    const float* x        = (const float*)d_in[0];
    const int*   src      = (const int*)d_in[1];
    const int*   dst      = (const int*)d_in[2];
    const float* p        = (const float*)d_in[3];
    const int*   batch    = (const int*)d_in[4];
    const int*   root_ptr = (const int*)d_in[5];
    // d_in[6] = num_graphs (256, hard-coded)
    const float* Wl1  = (const float*)d_in[7];
    const float* Wr1  = (const float*)d_in[8];
    const float* b1   = (const float*)d_in[9];
    const float* Wl2  = (const float*)d_in[10];
    const float* Wr2  = (const float*)d_in[11];
    const float* b2   = (const float*)d_in[12];
    const float* Wlin = (const float*)d_in[13];
    const float* blin = (const float*)d_in[14];
    float* out = (float*)d_out;

    // workspace layout (256B aligned slabs)
    size_t off = 0;
    char* base = (char*)d_ws;
    auto alloc = [&](size_t bytes) -> void* {
        void* q = base + off;
        off += (bytes + 255) & ~(size_t)255;
        return q;
    };
    int*            row_ptr   = (int*)  alloc((N_NODES + 1) * sizeof(int));
    int*            graph_ptr = (int*)  alloc((N_GRAPHS + 1) * sizeof(int));
    float*          inv_deg   = (float*)alloc(N_NODES * sizeof(float));
    unsigned short* Wl1t = (unsigned short*)alloc(256 * 256 * 2);
    unsigned short* Wr1t = (unsigned short*)alloc(256 * 256 * 2);
    unsigned short* Wl2t = (unsigned short*)alloc(256 * 256 * 2);
    unsigned short* Wr2t = (unsigned short*)alloc(256 * 256 * 2);
    unsigned short* xb   = (unsigned short*)alloc((size_t)N_NODES * 256 * 2);
    unsigned short* aggb = (unsigned short*)alloc((size_t)N_NODES * 256 * 2);
    unsigned short* h1   = (unsigned short*)alloc((size_t)N_NODES * 256 * 2);
    unsigned short* h2   = (unsigned short*)alloc((size_t)N_NODES * 256 * 2);
    float*          feat = (float*)alloc((size_t)N_GRAPHS * 512 * sizeof(float));
    (void)ws_size; (void)n_in; (void)in_sizes; (void)out_size;

    preprocess<<<13720, 256, 0, stream>>>(x, xb, Wl1, Wr1, Wl2, Wr2,
                                          Wl1t, Wr1t, Wl2t, Wr2t,
                                          dst, batch, row_ptr, graph_ptr, inv_deg);

    dim3 ggrid((N_NODES + 127) / 128);

    // conv1: h1 = relu(agg(x)@Wl1 + x@Wr1 + b1)
    aggregate<<<N_NODES / 4, 256, 0, stream>>>(xb, src, row_ptr, inv_deg, aggb);
    gemm_fused<<<ggrid, 512, 0, stream>>>(aggb, xb, Wl1t, Wr1t, b1, h1, N_NODES, 1);

    // conv2: h2 = agg(h1)@Wl2 + h1@Wr2 + b2
    aggregate<<<N_NODES / 4, 256, 0, stream>>>(h1, src, row_ptr, inv_deg, aggb);
    gemm_fused<<<ggrid, 512, 0, stream>>>(aggb, h1, Wl2t, Wr2t, b2, h2, N_NODES, 0);

    // pool + root gather + final linear
    pool_feat<<<N_GRAPHS, 256, 0, stream>>>(h2, p, graph_ptr, root_ptr, feat);
    final_gemm<<<N_GRAPHS, 128, 0, stream>>>(feat, Wlin, blin, out);
}